// Round 6
// baseline (16593.623 us; speedup 1.0000x reference)
//
#include <hip/hip_runtime.h>

// 2-layer LSTM (B=256,T=512,D=64,H=512) + FC(last step), MI355X gfx950.
// Round 6: cached-load exchange protocol.
//   h0 -> FULL HISTORY [t][b][d] (128 MB): every address written once =>
//   consumers can never hold stale copies => plain cached loads, NO acquire.
//   Producers: plain stores + RELEASE flag store (vmcnt drain + wbL2 -> IF$).
//   Same-XCD redundant readers now share one IF$ fill via L2 (vs R5's 40
//   MB/step of L2-bypassing sc1 reads = the 18.7 us/step).
//   h1 stays 2-slot (L1-internal): RELEASE publish + one ACQUIRE poll (inv).
//   L0 fully decoupled from L1 (no backpressure; L1 lags freely off-chain).
// Grid: 512 blocks x 256 thr, 2/CU. Blocks 0..255 = L0 (8g x 32s, 32 rows x
// 16 dims); 256..511 = L1 (4G x 64s1, 64 rows x 8 dims). Waves = K-quarters.

#define BATCH 256
#define SEQ   512
#define DIN   64
#define HID   512

typedef _Float16 f16_t;
typedef __attribute__((ext_vector_type(8))) _Float16 f16x8;
typedef __attribute__((ext_vector_type(4))) float    f32x4;

#define SCOPE_AGT __HIP_MEMORY_SCOPE_AGENT

__device__ inline f16x8 cvt8(const float* __restrict__ p) {
    f16x8 r;
#pragma unroll
    for (int j = 0; j < 8; j++) r[j] = (_Float16)p[j];
    return r;
}

__device__ inline f16x8 cvt8v(f32x4 lo, f32x4 hi) {
    f16x8 r;
#pragma unroll
    for (int j = 0; j < 4; j++) { r[j] = (_Float16)lo[j]; r[4 + j] = (_Float16)hi[j]; }
    return r;
}

// Plain cached h-pair store (2 x f16 packed in a dword).
__device__ inline void sth2(f16_t* base_even, float h, float hn) {
    union { struct { _Float16 lo, hi; } s; unsigned u; } pk;
    pk.s.lo = (_Float16)h; pk.s.hi = (_Float16)hn;
    *(unsigned*)base_even = pk.u;
}

// Wave polls 64 flag dwords (lane i -> p[i]) with relaxed coherence-point loads.
__device__ inline void pollw(unsigned* p, unsigned need) {
    for (;;) {
        unsigned v = __hip_atomic_load(p, __ATOMIC_RELAXED, SCOPE_AGT);
        if (__all((int)(v >= need))) break;
        __builtin_amdgcn_s_sleep(1);
    }
}

__device__ inline float sgm(float v) { return 1.f / (1.f + __expf(-v)); }
__device__ inline float th(float v)  { return 1.f - 2.f / (__expf(2.f * v) + 1.f); }

__global__ __launch_bounds__(256, 2) void lstm_pipe(
    const float* __restrict__ x,
    const float* __restrict__ wih0, const float* __restrict__ whh0,
    const float* __restrict__ bih0, const float* __restrict__ bhh0,
    const float* __restrict__ wih1, const float* __restrict__ whh1,
    const float* __restrict__ bih1, const float* __restrict__ bhh1,
    unsigned* __restrict__ f0m, unsigned* __restrict__ f1,
    f16_t* __restrict__ h1buf, f16_t* __restrict__ h0hist)
{
    __shared__ f32x4 red[4][8][64];      // [wave][acc-slot][lane]  32 KB

    const int tid  = threadIdx.x;
    const int w    = tid >> 6, lane = tid & 63;
    const int quad = lane >> 4, col = lane & 15;
    const int bid  = blockIdx.x;

    if (bid < 256) {
        // ======================= L0 block: (g, s) =======================
        const int g = bid & 7, s = bid >> 3;
        unsigned* myf = f0m + g * 64;            // 64 flags: [s*2 + m]

        f16x8 Wb[20];
#pragma unroll
        for (int i = 0; i < 4; i++) {            // h K-blocks: kb = w*4+i
            const int k0 = (w * 4 + i) * 32 + quad * 8;
#pragma unroll
            for (int nt = 0; nt < 4; nt++) {
                const int gr = nt * HID + s * 16 + col;
                Wb[i * 4 + nt] = cvt8(whh0 + (size_t)gr * HID + k0);
            }
        }
        if (w < 2) {                             // x K-block: dims w*32..+32
#pragma unroll
            for (int nt = 0; nt < 4; nt++) {
                const int gr = nt * HID + s * 16 + col;
                Wb[16 + nt] = cvt8(wih0 + (size_t)gr * DIN + w * 32 + quad * 8);
            }
        } else {
#pragma unroll
            for (int nt = 0; nt < 4; nt++) Wb[16 + nt] = (f16x8)(_Float16)0;
        }
#pragma unroll
        for (int i = 0; i < 20; i++) asm volatile("" : "+v"(Wb[i]));  // anti-remat

        float bias[4] = {0, 0, 0, 0};
        if (w < 2) {
#pragma unroll
            for (int nt = 0; nt < 4; nt++) {
                const int gr = nt * HID + s * 16 + col;
                bias[nt] = bih0[gr] + bhh0[gr];
            }
        }
        float cst[4] = {0, 0, 0, 0};

        for (int it = 0; it < SEQ; ++it) {
            // x prefetch (independent of poll)
            f32x4 xr[4];
            if (w < 2) {
#pragma unroll
                for (int m = 0; m < 2; m++) {
                    const float* px = x + ((size_t)(g * 32 + m * 16 + col) * SEQ + it) * DIN + w * 32 + quad * 8;
                    xr[m * 2]     = *(const f32x4*)px;
                    xr[m * 2 + 1] = *(const f32x4*)(px + 4);
                }
            }
            if (it >= 1) pollw(myf + lane, (unsigned)it);   // all (s,m) of own group done step it-1

            f32x4 acc[8];
#pragma unroll
            for (int j = 0; j < 8; j++) acc[j] = (f32x4){0.f, 0.f, 0.f, 0.f};

            if (it > 0) {
                const f16_t* h0b = h0hist + (size_t)(it - 1) * BATCH * HID;  // unique per t -> no stale copies
#pragma unroll
                for (int i = 0; i < 4; i++) {
                    const int kb = w * 4 + i;
#pragma unroll
                    for (int m = 0; m < 2; m++) {
                        f16x8 a = *(const f16x8*)(h0b + (size_t)(g * 32 + m * 16 + col) * HID + kb * 32 + quad * 8);
#pragma unroll
                        for (int nt = 0; nt < 4; nt++)
                            acc[m * 4 + nt] = __builtin_amdgcn_mfma_f32_16x16x32_f16(a, Wb[i * 4 + nt], acc[m * 4 + nt], 0, 0, 0);
                    }
                }
            }
            if (w < 2) {
#pragma unroll
                for (int m = 0; m < 2; m++) {
                    f16x8 a = cvt8v(xr[m * 2], xr[m * 2 + 1]);
#pragma unroll
                    for (int nt = 0; nt < 4; nt++)
                        acc[m * 4 + nt] = __builtin_amdgcn_mfma_f32_16x16x32_f16(a, Wb[16 + nt], acc[m * 4 + nt], 0, 0, 0);
                }
            }
#pragma unroll
            for (int j = 0; j < 8; j++) red[w][j][lane] = acc[j];
            __syncthreads();                                 // partials published

            if (w < 2) {                                     // cell: wave w -> m-tile w
                const int m = w;
                f32x4 gate[4];
#pragma unroll
                for (int nt = 0; nt < 4; nt++) {
                    f32x4 v = red[0][m * 4 + nt][lane];
#pragma unroll
                    for (int ww = 1; ww < 4; ww++) {
                        f32x4 p = red[ww][m * 4 + nt][lane];
#pragma unroll
                        for (int r = 0; r < 4; r++) v[r] += p[r];
                    }
                    gate[nt] = v;
                }
                f16_t* hout = h0hist + (size_t)it * BATCH * HID;
#pragma unroll
                for (int r = 0; r < 4; r++) {
                    float iv = sgm(gate[0][r] + bias[0]), fv = sgm(gate[1][r] + bias[1]);
                    float gv = th(gate[2][r] + bias[2]),  ov = sgm(gate[3][r] + bias[3]);
                    float c = fv * cst[r] + iv * gv;
                    cst[r] = c;
                    float h = ov * th(c);
                    float hn = __shfl_down(h, 1);
                    if ((lane & 1) == 0)
                        sth2(hout + (size_t)(g * 32 + m * 16 + quad * 4 + r) * HID + s * 16 + col, h, hn);
                }
                // RELEASE: drains this wave's h stores + wbL2, then flag.
                if (lane == 0)
                    __hip_atomic_store(myf + s * 2 + m, (unsigned)(it + 1), __ATOMIC_RELEASE, SCOPE_AGT);
            }
            __syncthreads();                                 // LDS red reuse guard
        }
    } else {
        // ======================= L1 block: (G, s1) ======================
        const int idx = bid - 256;
        const int G = idx & 3, s1 = idx >> 2;
        unsigned* myf1 = f1 + G * 64;            // 64 flags: [s1]

        f16x8 Wb[16];
#pragma unroll
        for (int i = 0; i < 8; i++) {            // kb = w*8+i over K=1024
            const int kb = w * 8 + i;
            const int k0 = kb * 32 + quad * 8;
#pragma unroll
            for (int n2 = 0; n2 < 2; n2++) {
                const int gate = n2 * 2 + (col >> 3);
                const int grow = gate * HID + s1 * 8 + (col & 7);
                const float* src = (kb < 16) ? (wih1 + (size_t)grow * HID + k0)
                                             : (whh1 + (size_t)grow * HID + (k0 - 512));
                Wb[i * 2 + n2] = cvt8(src);
            }
        }
#pragma unroll
        for (int i = 0; i < 16; i++) asm volatile("" : "+v"(Wb[i]));  // anti-remat

        const int d = s1 * 8 + (col & 7);
        const float bi = bih1[d] + bhh1[d];
        const float bf = bih1[HID + d] + bhh1[HID + d];
        const float bg = bih1[2 * HID + d] + bhh1[2 * HID + d];
        const float bo = bih1[3 * HID + d] + bhh1[3 * HID + d];
        float cst[4] = {0, 0, 0, 0};

        for (int it = 1; it <= SEQ; ++it) {
            const int t = it - 1;
            // h0[t] ready: both source groups finished step t (flags >= t+1).
            pollw(f0m + (2 * G) * 64 + lane, (unsigned)it);
            pollw(f0m + (2 * G + 1) * 64 + lane, (unsigned)it);
            if (t >= 1) {
                // lockstep among group-mates: h1[t-1] ready AND slot t&1 free.
                pollw(myf1 + lane, (unsigned)t);
                // ACQUIRE (inv): h1 slots are reused addresses -> drop stale copies.
                (void)__hip_atomic_load(myf1 + s1, __ATOMIC_ACQUIRE, SCOPE_AGT);
            }

            f32x4 acc[8];
#pragma unroll
            for (int j = 0; j < 8; j++) acc[j] = (f32x4){0.f, 0.f, 0.f, 0.f};

            const f16_t* h0b = h0hist + (size_t)t * BATCH * HID;
            const f16_t* h1r = h1buf + (size_t)((t - 1) & 1) * BATCH * HID;
#pragma unroll
            for (int i = 0; i < 8; i++) {
                const int kb = w * 8 + i;
                if (kb < 16) {
#pragma unroll
                    for (int mt = 0; mt < 4; mt++) {
                        f16x8 a = *(const f16x8*)(h0b + (size_t)(G * 64 + mt * 16 + col) * HID + kb * 32 + quad * 8);
#pragma unroll
                        for (int n2 = 0; n2 < 2; n2++)
                            acc[mt * 2 + n2] = __builtin_amdgcn_mfma_f32_16x16x32_f16(a, Wb[i * 2 + n2], acc[mt * 2 + n2], 0, 0, 0);
                    }
                } else if (t > 0) {
#pragma unroll
                    for (int mt = 0; mt < 4; mt++) {
                        f16x8 a = *(const f16x8*)(h1r + (size_t)(G * 64 + mt * 16 + col) * HID + (kb - 16) * 32 + quad * 8);
#pragma unroll
                        for (int n2 = 0; n2 < 2; n2++)
                            acc[mt * 2 + n2] = __builtin_amdgcn_mfma_f32_16x16x32_f16(a, Wb[i * 2 + n2], acc[mt * 2 + n2], 0, 0, 0);
                    }
                }
            }
#pragma unroll
            for (int j = 0; j < 8; j++) red[w][j][lane] = acc[j];
            __syncthreads();                                 // partials published

            {                                                // cell: wave w -> m-tile w
                const int mt = w;
                f32x4 t0 = red[0][mt * 2][lane], t1 = red[0][mt * 2 + 1][lane];
#pragma unroll
                for (int ww = 1; ww < 4; ww++) {
                    f32x4 p0 = red[ww][mt * 2][lane], p1 = red[ww][mt * 2 + 1][lane];
#pragma unroll
                    for (int r = 0; r < 4; r++) { t0[r] += p0[r]; t1[r] += p1[r]; }
                }
                f16_t* hout = h1buf + (size_t)(t & 1) * BATCH * HID;
#pragma unroll
                for (int r = 0; r < 4; r++) {
                    float p0 = __shfl_xor(t0[r], 8), p1 = __shfl_xor(t1[r], 8);
                    float iv = sgm(t0[r] + bi), fv = sgm(p0 + bf);
                    float gv = th(t1[r] + bg),  ov = sgm(p1 + bo);
                    float c = fv * cst[r] + iv * gv;          // lanes col>=8: unused garbage
                    cst[r] = c;
                    float h = ov * th(c);
                    float hn = __shfl_down(h, 1);
                    if ((col & 9) == 0)                       // col even and < 8
                        sth2(hout + (size_t)(G * 64 + mt * 16 + quad * 4 + r) * HID + s1 * 8 + col, h, hn);
                }
            }
            __syncthreads();                                 // drain all waves' h1 stores
            if (tid == 0)
                __hip_atomic_store(myf1 + s1, (unsigned)it, __ATOMIC_RELEASE, SCOPE_AGT);
        }
    }
}

// out[b] = dot(h1[511][b], fc_w) + fc_b ; slot = 511&1 = 1.
__global__ void fc_k(const f16_t* __restrict__ h1buf, const float* __restrict__ fcw,
                     const float* __restrict__ fcb, float* __restrict__ out)
{
    const int b = blockIdx.x, lane = threadIdx.x;
    const f16_t* hp = h1buf + ((size_t)(BATCH + b)) * HID;
    float sum = 0.f;
#pragma unroll
    for (int j = 0; j < 8; j++) {
        const int k = lane * 8 + j;
        sum += (float)hp[k] * fcw[k];
    }
#pragma unroll
    for (int off = 32; off; off >>= 1) sum += __shfl_down(sum, off);
    if (lane == 0) out[b] = sum + fcb[0];
}

extern "C" void kernel_launch(void* const* d_in, const int* in_sizes, int n_in,
                              void* d_out, int out_size, void* d_ws, size_t ws_size,
                              hipStream_t stream)
{
    const float* x    = (const float*)d_in[0];
    const float* wih0 = (const float*)d_in[1];
    const float* whh0 = (const float*)d_in[2];
    const float* bih0 = (const float*)d_in[3];
    const float* bhh0 = (const float*)d_in[4];
    const float* wih1 = (const float*)d_in[5];
    const float* whh1 = (const float*)d_in[6];
    const float* bih1 = (const float*)d_in[7];
    const float* bhh1 = (const float*)d_in[8];
    const float* fcw  = (const float*)d_in[9];
    const float* fcb  = (const float*)d_in[10];
    float* out = (float*)d_out;

    unsigned char* ws = (unsigned char*)d_ws;
    unsigned* f0m = (unsigned*)ws;                // 8 groups * 64 = 2 KB
    unsigned* f1  = (unsigned*)(ws + 2048);       // 4 groups * 64 = 1 KB
    f16_t* h1buf  = (f16_t*)(ws + 4096);          // 2 slots * 256*512 f16 = 512 KB
    f16_t* h0hist = (f16_t*)(ws + 4096 + 2 * BATCH * HID * sizeof(f16_t));  // 512*256*512*2B = 128 MB

    hipMemsetAsync(ws, 0, 4096, stream);          // zero epoch flags
    lstm_pipe<<<dim3(512), dim3(256), 0, stream>>>(x, wih0, whh0, bih0, bhh0,
                                                   wih1, whh1, bih1, bhh1,
                                                   f0m, f1, h1buf, h0hist);
    fc_k<<<dim3(BATCH), dim3(64), 0, stream>>>(h1buf, fcw, fcb, out);
}

// Round 7
// 6536.214 us; speedup vs baseline: 2.5387x; 2.5387x over previous
//
#include <hip/hip_runtime.h>

// 2-layer LSTM (B=256,T=512,D=64,H=512) + FC(last step), MI355X gfx950.
// Round 7: R5 structure + fixed exchange protocol.
//   h0 -> FULL 128MB history (write-once): producers store sc0sc1 (IF$; L2
//   never dirty => NO wbL2 anywhere), per-wave s_waitcnt vmcnt(0), RELAXED
//   flag store. Consumers use PLAIN CACHED loads (write-once = never stale;
//   L2 absorbs the 32-64x cross-block redundancy that killed R5 at IF$).
//   Flags: per-producer dwords, plain stores (no RMW), ONE poller wave per
//   block + barrier, s_sleep(4) backoff (kills R2/R5's same-line load storm).
//   L0 cell-waves publish flags EARLY (own-store drain, no block barrier).
//   h1: 2-slot sc0sc1 ping-pong (G-local, off critical chain), R5 semantics.
// Grid: 512 blocks x 256 thr, 2/CU. Blocks 0..255 = L0 (8g x 32s: 32 rows x
// 16 dims); 256..511 = L1 (4G x 64s1: 64 rows x 8 dims). Waves = K-quarters.

#define BATCH 256
#define SEQ   512
#define DIN   64
#define HID   512

typedef _Float16 f16_t;
typedef __attribute__((ext_vector_type(8))) _Float16 f16x8;
typedef __attribute__((ext_vector_type(4))) float    f32x4;

#define SCOPE_AGT __HIP_MEMORY_SCOPE_AGENT

__device__ inline f16x8 cvt8(const float* __restrict__ p) {
    f16x8 r;
#pragma unroll
    for (int j = 0; j < 8; j++) r[j] = (_Float16)p[j];
    return r;
}

__device__ inline f16x8 cvt8v(f32x4 lo, f32x4 hi) {
    f16x8 r;
#pragma unroll
    for (int j = 0; j < 4; j++) { r[j] = (_Float16)lo[j]; r[4 + j] = (_Float16)hi[j]; }
    return r;
}

// 16B coherence-point load (h1 slots only; bypasses L1/L2 -> never stale).
__device__ inline f16x8 ldx8(const f16_t* p) {
    const unsigned long long* q = (const unsigned long long*)p;
    unsigned long long a = __hip_atomic_load(q,     __ATOMIC_RELAXED, SCOPE_AGT);
    unsigned long long b = __hip_atomic_load(q + 1, __ATOMIC_RELAXED, SCOPE_AGT);
    union { unsigned long long u[2]; f16x8 v; } c;
    c.u[0] = a; c.u[1] = b;
    return c.v;
}

// Coherent h-pair store (dword to IF$).
__device__ inline void sth2a(f16_t* base_even, float h, float hn) {
    union { struct { _Float16 lo, hi; } s; unsigned u; } pk;
    pk.s.lo = (_Float16)h; pk.s.hi = (_Float16)hn;
    __hip_atomic_store((unsigned*)base_even, pk.u, __ATOMIC_RELAXED, SCOPE_AGT);
}

// Poller-wave: lane i watches p[i] (64 contiguous dwords).
__device__ inline void pollw(const unsigned* p, unsigned need, int lane) {
    for (;;) {
        unsigned v = __hip_atomic_load(p + lane, __ATOMIC_RELAXED, SCOPE_AGT);
        if (__all((int)(v >= need))) break;
        __builtin_amdgcn_s_sleep(4);
    }
}

// L1 combined poll: two L0 flag arrays >= na, optionally own f1 array >= nc.
__device__ inline void poll_l1(const unsigned* a, const unsigned* b, unsigned na,
                               const unsigned* c, unsigned nc, bool chk_c, int lane) {
    for (;;) {
        unsigned va = __hip_atomic_load(a + lane, __ATOMIC_RELAXED, SCOPE_AGT);
        unsigned vb = __hip_atomic_load(b + lane, __ATOMIC_RELAXED, SCOPE_AGT);
        unsigned vc = chk_c ? __hip_atomic_load(c + lane, __ATOMIC_RELAXED, SCOPE_AGT) : 0xffffffffu;
        if (__all((int)((va >= na) & (vb >= na) & (vc >= nc)))) break;
        __builtin_amdgcn_s_sleep(4);
    }
}

__device__ inline float sgm(float v) { return 1.f / (1.f + __expf(-v)); }
__device__ inline float th(float v)  { return 1.f - 2.f / (__expf(2.f * v) + 1.f); }

__global__ __launch_bounds__(256, 2) void lstm_pipe(
    const float* __restrict__ x,
    const float* __restrict__ wih0, const float* __restrict__ whh0,
    const float* __restrict__ bih0, const float* __restrict__ bhh0,
    const float* __restrict__ wih1, const float* __restrict__ whh1,
    const float* __restrict__ bih1, const float* __restrict__ bhh1,
    unsigned* __restrict__ f0m, unsigned* __restrict__ f1,
    f16_t* __restrict__ h1buf, f16_t* __restrict__ h0hist)
{
    __shared__ f32x4 red[4][8][64];      // [wave][acc-slot][lane]  32 KB

    const int tid  = threadIdx.x;
    const int w    = tid >> 6, lane = tid & 63;
    const int quad = lane >> 4, col = lane & 15;
    const int bid  = blockIdx.x;

    if (bid < 256) {
        // ======================= L0 block: (g, s) =======================
        const int g = bid & 7, s = bid >> 3;
        unsigned* myf = f0m + g * 64;            // 64 flags: [s*2 + m], value = it+1

        f16x8 Wb[20];
#pragma unroll
        for (int i = 0; i < 4; i++) {            // h K-blocks: kb = w*4+i
            const int k0 = (w * 4 + i) * 32 + quad * 8;
#pragma unroll
            for (int nt = 0; nt < 4; nt++) {
                const int gr = nt * HID + s * 16 + col;
                Wb[i * 4 + nt] = cvt8(whh0 + (size_t)gr * HID + k0);
            }
        }
        if (w < 2) {                             // x K-block: dims w*32..+32
#pragma unroll
            for (int nt = 0; nt < 4; nt++) {
                const int gr = nt * HID + s * 16 + col;
                Wb[16 + nt] = cvt8(wih0 + (size_t)gr * DIN + w * 32 + quad * 8);
            }
        } else {
#pragma unroll
            for (int nt = 0; nt < 4; nt++) Wb[16 + nt] = (f16x8)(_Float16)0;
        }
#pragma unroll
        for (int i = 0; i < 20; i++) asm volatile("" : "+v"(Wb[i]));  // anti-remat

        float bias[4] = {0, 0, 0, 0};
        if (w < 2) {
#pragma unroll
            for (int nt = 0; nt < 4; nt++) {
                const int gr = nt * HID + s * 16 + col;
                bias[nt] = bih0[gr] + bhh0[gr];
            }
        }
        float cst[4] = {0, 0, 0, 0};

        for (int it = 0; it < SEQ; ++it) {
            // x prefetch first (loads in flight during the poll)
            f32x4 xr[4];
            if (w < 2) {
#pragma unroll
                for (int m = 0; m < 2; m++) {
                    const float* px = x + ((size_t)(g * 32 + m * 16 + col) * SEQ + it) * DIN + w * 32 + quad * 8;
                    xr[m * 2]     = *(const f32x4*)px;
                    xr[m * 2 + 1] = *(const f32x4*)(px + 4);
                }
            }
            if (w == 0 && it >= 1) pollw(myf, (unsigned)it, lane);
            __syncthreads();                     // A: gate all waves on poll; also red-reuse guard

            f32x4 acc[8];
#pragma unroll
            for (int j = 0; j < 8; j++) acc[j] = (f32x4){0.f, 0.f, 0.f, 0.f};

            if (it > 0) {
                // plain CACHED loads: history addresses are write-once -> never stale
                const f16_t* h0b = h0hist + (size_t)(it - 1) * BATCH * HID;
#pragma unroll
                for (int i = 0; i < 4; i++) {
                    const int kb = w * 4 + i;
#pragma unroll
                    for (int m = 0; m < 2; m++) {
                        f16x8 a = *(const f16x8*)(h0b + (size_t)(g * 32 + m * 16 + col) * HID + kb * 32 + quad * 8);
#pragma unroll
                        for (int nt = 0; nt < 4; nt++)
                            acc[m * 4 + nt] = __builtin_amdgcn_mfma_f32_16x16x32_f16(a, Wb[i * 4 + nt], acc[m * 4 + nt], 0, 0, 0);
                    }
                }
            }
            if (w < 2) {
#pragma unroll
                for (int m = 0; m < 2; m++) {
                    f16x8 a = cvt8v(xr[m * 2], xr[m * 2 + 1]);
#pragma unroll
                    for (int nt = 0; nt < 4; nt++)
                        acc[m * 4 + nt] = __builtin_amdgcn_mfma_f32_16x16x32_f16(a, Wb[16 + nt], acc[m * 4 + nt], 0, 0, 0);
                }
            }
#pragma unroll
            for (int j = 0; j < 8; j++) red[w][j][lane] = acc[j];
            __syncthreads();                     // B: partials published

            if (w < 2) {                         // cell: wave w -> m-tile w
                const int m = w;
                f32x4 gate[4];
#pragma unroll
                for (int nt = 0; nt < 4; nt++) {
                    f32x4 v = red[0][m * 4 + nt][lane];
#pragma unroll
                    for (int ww = 1; ww < 4; ww++) {
                        f32x4 p = red[ww][m * 4 + nt][lane];
#pragma unroll
                        for (int r = 0; r < 4; r++) v[r] += p[r];
                    }
                    gate[nt] = v;
                }
                f16_t* hout = h0hist + (size_t)it * BATCH * HID;
#pragma unroll
                for (int r = 0; r < 4; r++) {
                    float iv = sgm(gate[0][r] + bias[0]), fv = sgm(gate[1][r] + bias[1]);
                    float gv = th(gate[2][r] + bias[2]),  ov = sgm(gate[3][r] + bias[3]);
                    float c = fv * cst[r] + iv * gv;
                    cst[r] = c;
                    float h = ov * th(c);
                    float hn = __shfl_down(h, 1);
                    if ((lane & 1) == 0)
                        sth2a(hout + (size_t)(g * 32 + m * 16 + quad * 4 + r) * HID + s * 16 + col, h, hn);
                }
                // EARLY publish: own sc0sc1 stores acked at IF$, then relaxed flag.
                asm volatile("s_waitcnt vmcnt(0)" ::: "memory");
                if (lane == 0)
                    __hip_atomic_store(myf + s * 2 + m, (unsigned)(it + 1), __ATOMIC_RELAXED, SCOPE_AGT);
            }
            // no barrier here: next iter's barrier A guards LDS reuse
        }
    } else {
        // ======================= L1 block: (G, s1) ======================
        const int idx = bid - 256;
        const int G = idx & 3, s1 = idx >> 2;
        unsigned* myf1 = f1 + G * 64;            // 64 flags: [s1], value = it

        f16x8 Wb[16];
#pragma unroll
        for (int i = 0; i < 8; i++) {            // kb = w*8+i over K=1024
            const int kb = w * 8 + i;
            const int k0 = kb * 32 + quad * 8;
#pragma unroll
            for (int n2 = 0; n2 < 2; n2++) {
                const int gate = n2 * 2 + (col >> 3);
                const int grow = gate * HID + s1 * 8 + (col & 7);
                const float* src = (kb < 16) ? (wih1 + (size_t)grow * HID + k0)
                                             : (whh1 + (size_t)grow * HID + (k0 - 512));
                Wb[i * 2 + n2] = cvt8(src);
            }
        }
#pragma unroll
        for (int i = 0; i < 16; i++) asm volatile("" : "+v"(Wb[i]));  // anti-remat

        const int d = s1 * 8 + (col & 7);
        const float bi = bih1[d] + bhh1[d];
        const float bf = bih1[HID + d] + bhh1[HID + d];
        const float bg = bih1[2 * HID + d] + bhh1[2 * HID + d];
        const float bo = bih1[3 * HID + d] + bhh1[3 * HID + d];
        float cst[4] = {0, 0, 0, 0};

        for (int it = 1; it <= SEQ; ++it) {
            const int t = it - 1;
            if (w == 0)
                poll_l1(f0m + (2 * G) * 64, f0m + (2 * G + 1) * 64, (unsigned)it,
                        myf1, (unsigned)(it - 1), it >= 2, lane);
            __syncthreads();                     // A: gate + red-reuse guard

            f32x4 acc[8];
#pragma unroll
            for (int j = 0; j < 8; j++) acc[j] = (f32x4){0.f, 0.f, 0.f, 0.f};

            const f16_t* h0b = h0hist + (size_t)t * BATCH * HID;      // cached, write-once
            const f16_t* h1r = h1buf + (size_t)((t - 1) & 1) * BATCH * HID;
#pragma unroll
            for (int i = 0; i < 8; i++) {
                const int kb = w * 8 + i;
                if (kb < 16) {
#pragma unroll
                    for (int mt = 0; mt < 4; mt++) {
                        f16x8 a = *(const f16x8*)(h0b + (size_t)(G * 64 + mt * 16 + col) * HID + kb * 32 + quad * 8);
#pragma unroll
                        for (int n2 = 0; n2 < 2; n2++)
                            acc[mt * 2 + n2] = __builtin_amdgcn_mfma_f32_16x16x32_f16(a, Wb[i * 2 + n2], acc[mt * 2 + n2], 0, 0, 0);
                    }
                } else if (t > 0) {
#pragma unroll
                    for (int mt = 0; mt < 4; mt++) {
                        f16x8 a = ldx8(h1r + (size_t)(G * 64 + mt * 16 + col) * HID + (kb - 16) * 32 + quad * 8);
#pragma unroll
                        for (int n2 = 0; n2 < 2; n2++)
                            acc[mt * 2 + n2] = __builtin_amdgcn_mfma_f32_16x16x32_f16(a, Wb[i * 2 + n2], acc[mt * 2 + n2], 0, 0, 0);
                    }
                }
            }
#pragma unroll
            for (int j = 0; j < 8; j++) red[w][j][lane] = acc[j];
            __syncthreads();                     // B: partials published

            {                                    // cell: wave w -> m-tile w
                const int mt = w;
                f32x4 t0 = red[0][mt * 2][lane], t1 = red[0][mt * 2 + 1][lane];
#pragma unroll
                for (int ww = 1; ww < 4; ww++) {
                    f32x4 p0 = red[ww][mt * 2][lane], p1 = red[ww][mt * 2 + 1][lane];
#pragma unroll
                    for (int r = 0; r < 4; r++) { t0[r] += p0[r]; t1[r] += p1[r]; }
                }
                f16_t* hout = h1buf + (size_t)(t & 1) * BATCH * HID;
#pragma unroll
                for (int r = 0; r < 4; r++) {
                    float p0 = __shfl_xor(t0[r], 8), p1 = __shfl_xor(t1[r], 8);
                    float iv = sgm(t0[r] + bi), fv = sgm(p0 + bf);
                    float gv = th(t1[r] + bg),  ov = sgm(p1 + bo);
                    float c = fv * cst[r] + iv * gv;      // lanes col>=8: unused garbage
                    cst[r] = c;
                    float h = ov * th(c);
                    float hn = __shfl_down(h, 1);
                    if ((col & 9) == 0)                   // col even and < 8
                        sth2a(hout + (size_t)(G * 64 + mt * 16 + quad * 4 + r) * HID + s1 * 8 + col, h, hn);
                }
            }
            __syncthreads();                     // C: all waves' h1 stores drained (vmcnt 0)
            if (tid == 0)
                __hip_atomic_store(myf1 + s1, (unsigned)it, __ATOMIC_RELAXED, SCOPE_AGT);
        }
    }
}

// out[b] = dot(h1[511][b], fc_w) + fc_b ; slot = 511&1 = 1.
// Kernel-entry acquire invalidates caches; h1 was stored sc0sc1 -> visible.
__global__ void fc_k(const f16_t* __restrict__ h1buf, const float* __restrict__ fcw,
                     const float* __restrict__ fcb, float* __restrict__ out)
{
    const int b = blockIdx.x, lane = threadIdx.x;
    const f16_t* hp = h1buf + ((size_t)(BATCH + b)) * HID;
    float sum = 0.f;
#pragma unroll
    for (int j = 0; j < 8; j++) {
        const int k = lane * 8 + j;
        sum += (float)hp[k] * fcw[k];
    }
#pragma unroll
    for (int off = 32; off; off >>= 1) sum += __shfl_down(sum, off);
    if (lane == 0) out[b] = sum + fcb[0];
}

extern "C" void kernel_launch(void* const* d_in, const int* in_sizes, int n_in,
                              void* d_out, int out_size, void* d_ws, size_t ws_size,
                              hipStream_t stream)
{
    const float* x    = (const float*)d_in[0];
    const float* wih0 = (const float*)d_in[1];
    const float* whh0 = (const float*)d_in[2];
    const float* bih0 = (const float*)d_in[3];
    const float* bhh0 = (const float*)d_in[4];
    const float* wih1 = (const float*)d_in[5];
    const float* whh1 = (const float*)d_in[6];
    const float* bih1 = (const float*)d_in[7];
    const float* bhh1 = (const float*)d_in[8];
    const float* fcw  = (const float*)d_in[9];
    const float* fcb  = (const float*)d_in[10];
    float* out = (float*)d_out;

    unsigned char* ws = (unsigned char*)d_ws;
    unsigned* f0m = (unsigned*)ws;                // 8 groups * 64 dwords = 2 KB
    unsigned* f1  = (unsigned*)(ws + 2048);       // 4 groups * 64 dwords = 1 KB
    f16_t* h1buf  = (f16_t*)(ws + 4096);          // 2 slots * 256*512 f16 = 512 KB
    f16_t* h0hist = (f16_t*)(ws + 4096 + 2 * BATCH * HID * sizeof(f16_t));  // 128 MB (R1-proven budget)

    hipMemsetAsync(ws, 0, 4096, stream);          // zero epoch flags
    lstm_pipe<<<dim3(512), dim3(256), 0, stream>>>(x, wih0, whh0, bih0, bhh0,
                                                   wih1, whh1, bih1, bhh1,
                                                   f0m, f1, h1buf, h0hist);
    fc_k<<<dim3(BATCH), dim3(64), 0, stream>>>(h1buf, fcw, fcb, out);
}

// Round 8
// 4763.169 us; speedup vs baseline: 3.4837x; 1.3722x over previous
//
#include <hip/hip_runtime.h>

// 2-layer LSTM (B=256,T=512,D=64,H=512) + FC(last step), MI355X gfx950.
// Round 8: ONE BLOCK PER CU (87KB LDS forces exclusivity), halved fan-in.
//   256 blocks x 256 thr. Blocks 0..127 = L0 (8g x 16s: 32 rows x 32 dims).
//   Blocks 128..255 = L1 (4G x 32s1: 64 rows x 16 dims). Waves = K-quarters.
//   R7 protocol kept: h0 -> 128MB write-once history, producers store sc0sc1
//   (IF$; L2 never dirty -> no wbL2), per-wave vmcnt(0) drain, RELAXED flag;
//   consumers use plain cached loads (write-once = never stale; L2 absorbs
//   cross-block redundancy). h1: 2-slot sc0sc1 ping-pong, G-local.
//   New: all 4 waves are cell waves (m x col-tile), each publishes its own
//   fine flag early; producers pre-warm their h0 store lines with discarded
//   agent-scope loads (IF$ fill off-chain, no L2 copies -> no staleness).

#define BATCH 256
#define SEQ   512
#define DIN   64
#define HID   512

typedef _Float16 f16_t;
typedef __attribute__((ext_vector_type(8))) _Float16 f16x8;
typedef __attribute__((ext_vector_type(4))) float    f32x4;

#define SCOPE_AGT __HIP_MEMORY_SCOPE_AGENT

__device__ inline f16x8 cvt8(const float* __restrict__ p) {
    f16x8 r;
#pragma unroll
    for (int j = 0; j < 8; j++) r[j] = (_Float16)p[j];
    return r;
}

__device__ inline f16x8 cvt8v(f32x4 lo, f32x4 hi) {
    f16x8 r;
#pragma unroll
    for (int j = 0; j < 4; j++) { r[j] = (_Float16)lo[j]; r[4 + j] = (_Float16)hi[j]; }
    return r;
}

// 16B coherence-point load (h1 slots; bypasses L1/L2 -> never stale).
__device__ inline f16x8 ldx8(const f16_t* p) {
    const unsigned long long* q = (const unsigned long long*)p;
    unsigned long long a = __hip_atomic_load(q,     __ATOMIC_RELAXED, SCOPE_AGT);
    unsigned long long b = __hip_atomic_load(q + 1, __ATOMIC_RELAXED, SCOPE_AGT);
    union { unsigned long long u[2]; f16x8 v; } c;
    c.u[0] = a; c.u[1] = b;
    return c.v;
}

// Coherent h-pair store (dword to IF$).
__device__ inline void sth2a(f16_t* base_even, float h, float hn) {
    union { struct { _Float16 lo, hi; } s; unsigned u; } pk;
    pk.s.lo = (_Float16)h; pk.s.hi = (_Float16)hn;
    __hip_atomic_store((unsigned*)base_even, pk.u, __ATOMIC_RELAXED, SCOPE_AGT);
}

// Poller wave: lane i watches p[i].
__device__ inline void pollw(const unsigned* p, unsigned need, int lane) {
    for (;;) {
        unsigned v = __hip_atomic_load(p + lane, __ATOMIC_RELAXED, SCOPE_AGT);
        if (__all((int)(v >= need))) break;
        __builtin_amdgcn_s_sleep(1);
    }
}

__device__ inline float sgm(float v) { return 1.f / (1.f + __expf(-v)); }
__device__ inline float th(float v)  { return 1.f - 2.f / (__expf(2.f * v) + 1.f); }

__global__ __launch_bounds__(256, 1) void lstm_pipe(
    const float* __restrict__ x,
    const float* __restrict__ wih0, const float* __restrict__ whh0,
    const float* __restrict__ bih0, const float* __restrict__ bhh0,
    const float* __restrict__ wih1, const float* __restrict__ whh1,
    const float* __restrict__ bih1, const float* __restrict__ bhh1,
    unsigned* __restrict__ f0m, unsigned* __restrict__ f1,
    f16_t* __restrict__ h1buf, f16_t* __restrict__ h0hist)
{
    // 87 KB: 2 blocks would need 174 KB > 160 KB -> guaranteed 1 block/CU.
    __shared__ f32x4 red[5][17][64];     // use [0..3][0..15][lane]

    const int tid  = threadIdx.x;
    const int w    = tid >> 6, lane = tid & 63;
    const int quad = lane >> 4, col = lane & 15;
    const int bid  = blockIdx.x;

    if (bid < 128) {
        // ============ L0 block: (g, s) -- 32 rows x 32 dims ============
        const int g = bid & 7, s = bid >> 3;           // s < 16
        unsigned* myf = f0m + g * 64;                  // flags [s*4+m*2+ct], val it+1
        const int mym = w & 1, myct = w >> 1;          // this wave's cell quarter

        f16x8 Wh[32];                                  // [i<4][ct<2][nt<4]
#pragma unroll
        for (int i = 0; i < 4; i++) {
            const int k0 = (w * 4 + i) * 32 + quad * 8;
#pragma unroll
            for (int ct = 0; ct < 2; ct++)
#pragma unroll
                for (int nt = 0; nt < 4; nt++) {
                    const int gr = nt * HID + s * 32 + ct * 16 + col;
                    Wh[i * 8 + ct * 4 + nt] = cvt8(whh0 + (size_t)gr * HID + k0);
                }
        }
        f16x8 Wx[8];
        if (w >= 2) {
#pragma unroll
            for (int ct = 0; ct < 2; ct++)
#pragma unroll
                for (int nt = 0; nt < 4; nt++) {
                    const int gr = nt * HID + s * 32 + ct * 16 + col;
                    Wx[ct * 4 + nt] = cvt8(wih0 + (size_t)gr * DIN + (w - 2) * 32 + quad * 8);
                }
        } else {
#pragma unroll
            for (int j = 0; j < 8; j++) Wx[j] = (f16x8)(_Float16)0;
        }
#pragma unroll
        for (int i = 0; i < 32; i++) asm volatile("" : "+v"(Wh[i]));
#pragma unroll
        for (int i = 0; i < 8; i++)  asm volatile("" : "+v"(Wx[i]));

        float bias[4];
#pragma unroll
        for (int nt = 0; nt < 4; nt++) {
            const int gr = nt * HID + s * 32 + myct * 16 + col;
            bias[nt] = bih0[gr] + bhh0[gr];
        }
        float cst[4] = {0, 0, 0, 0};

        for (int it = 0; it < SEQ; ++it) {
            // pre-warm own h0 store lines into IF$ (sc loads: no L2 copies)
            {
                const f16_t* hw = h0hist + (size_t)it * BATCH * HID;
                unsigned sink = 0;
#pragma unroll
                for (int r = 0; r < 4; r++) {
                    const unsigned* p = (const unsigned*)(hw +
                        (size_t)(g * 32 + mym * 16 + quad * 4 + r) * HID + s * 32 + myct * 16 + (col & ~1));
                    sink += __hip_atomic_load(p, __ATOMIC_RELAXED, SCOPE_AGT);
                }
                asm volatile("" : "+v"(sink));
            }
            // x prefetch (loads in flight during poll)
            f32x4 xr[4];
            if (w >= 2) {
#pragma unroll
                for (int m = 0; m < 2; m++) {
                    const float* px = x + ((size_t)(g * 32 + m * 16 + col) * SEQ + it) * DIN + (w - 2) * 32 + quad * 8;
                    xr[m * 2]     = *(const f32x4*)px;
                    xr[m * 2 + 1] = *(const f32x4*)(px + 4);
                }
            }
            if (w == 0 && it >= 1) pollw(myf, (unsigned)it, lane);
            __syncthreads();                            // A: gate + red-reuse guard

            f32x4 acc[16];
#pragma unroll
            for (int j = 0; j < 16; j++) acc[j] = (f32x4){0.f, 0.f, 0.f, 0.f};

            if (it > 0) {
                const f16_t* h0b = h0hist + (size_t)(it - 1) * BATCH * HID;   // write-once: cached loads
#pragma unroll
                for (int i = 0; i < 4; i++) {
                    const int kb = w * 4 + i;
#pragma unroll
                    for (int m = 0; m < 2; m++) {
                        f16x8 a = *(const f16x8*)(h0b + (size_t)(g * 32 + m * 16 + col) * HID + kb * 32 + quad * 8);
#pragma unroll
                        for (int ct = 0; ct < 2; ct++)
#pragma unroll
                            for (int nt = 0; nt < 4; nt++)
                                acc[m * 8 + ct * 4 + nt] = __builtin_amdgcn_mfma_f32_16x16x32_f16(
                                    a, Wh[i * 8 + ct * 4 + nt], acc[m * 8 + ct * 4 + nt], 0, 0, 0);
                    }
                }
            }
            if (w >= 2) {
#pragma unroll
                for (int m = 0; m < 2; m++) {
                    f16x8 a = cvt8v(xr[m * 2], xr[m * 2 + 1]);
#pragma unroll
                    for (int ct = 0; ct < 2; ct++)
#pragma unroll
                        for (int nt = 0; nt < 4; nt++)
                            acc[m * 8 + ct * 4 + nt] = __builtin_amdgcn_mfma_f32_16x16x32_f16(
                                a, Wx[ct * 4 + nt], acc[m * 8 + ct * 4 + nt], 0, 0, 0);
                }
            }
#pragma unroll
            for (int j = 0; j < 16; j++) red[w][j][lane] = acc[j];
            __syncthreads();                            // B: partials published

            // cell: wave (mym, myct) -> 16 rows x 16 dims
            f32x4 gate[4];
#pragma unroll
            for (int nt = 0; nt < 4; nt++) {
                f32x4 v = red[0][mym * 8 + myct * 4 + nt][lane];
#pragma unroll
                for (int ww = 1; ww < 4; ww++) {
                    f32x4 p = red[ww][mym * 8 + myct * 4 + nt][lane];
#pragma unroll
                    for (int r = 0; r < 4; r++) v[r] += p[r];
                }
                gate[nt] = v;
            }
            f16_t* hout = h0hist + (size_t)it * BATCH * HID;
#pragma unroll
            for (int r = 0; r < 4; r++) {
                float iv = sgm(gate[0][r] + bias[0]), fv = sgm(gate[1][r] + bias[1]);
                float gv = th(gate[2][r] + bias[2]),  ov = sgm(gate[3][r] + bias[3]);
                float c = fv * cst[r] + iv * gv;
                cst[r] = c;
                float h = ov * th(c);
                float hn = __shfl_down(h, 1);
                if ((lane & 1) == 0)
                    sth2a(hout + (size_t)(g * 32 + mym * 16 + quad * 4 + r) * HID + s * 32 + myct * 16 + col, h, hn);
            }
            asm volatile("s_waitcnt vmcnt(0)" ::: "memory");   // own stores acked at IF$
            if (lane == 0)
                __hip_atomic_store(myf + s * 4 + mym * 2 + myct, (unsigned)(it + 1), __ATOMIC_RELAXED, SCOPE_AGT);
        }
    } else {
        // ============ L1 block: (G, s1) -- 64 rows x 16 dims ============
        const int idx = bid - 128;
        const int G = idx & 3, s1 = idx >> 2;          // s1 < 32
        unsigned* myf1 = f1 + G * 32;                  // flags [s1], value = it

        f16x8 Wb[32];
#pragma unroll
        for (int i = 0; i < 8; i++) {                  // kb = w*8+i over K=1024
            const int kb = w * 8 + i;
            const int k0 = kb * 32 + quad * 8;
#pragma unroll
            for (int nt = 0; nt < 4; nt++) {
                const int grow = nt * HID + s1 * 16 + col;
                const float* src = (kb < 16) ? (wih1 + (size_t)grow * HID + k0)
                                             : (whh1 + (size_t)grow * HID + (k0 - 512));
                Wb[i * 4 + nt] = cvt8(src);
            }
        }
#pragma unroll
        for (int i = 0; i < 32; i++) asm volatile("" : "+v"(Wb[i]));

        const int d = s1 * 16 + col;
        const float bi = bih1[d] + bhh1[d];
        const float bf = bih1[HID + d] + bhh1[HID + d];
        const float bg = bih1[2 * HID + d] + bhh1[2 * HID + d];
        const float bo = bih1[3 * HID + d] + bhh1[3 * HID + d];
        float cst[4] = {0, 0, 0, 0};

        for (int it = 1; it <= SEQ; ++it) {
            const int t = it - 1;
            if (w == 0) {
                const unsigned* pa = f0m + (2 * G) * 64;
                const unsigned* pb = f0m + (2 * G + 1) * 64;
                const bool chk = (it >= 2);
                for (;;) {
                    unsigned va = __hip_atomic_load(pa + lane, __ATOMIC_RELAXED, SCOPE_AGT);
                    unsigned vb = __hip_atomic_load(pb + lane, __ATOMIC_RELAXED, SCOPE_AGT);
                    unsigned vc = chk ? __hip_atomic_load(myf1 + (lane & 31), __ATOMIC_RELAXED, SCOPE_AGT)
                                      : 0xffffffffu;
                    if (__all((int)((va >= (unsigned)it) & (vb >= (unsigned)it) & (vc >= (unsigned)(it - 1))))) break;
                    __builtin_amdgcn_s_sleep(1);
                }
            }
            __syncthreads();                            // A

            f32x4 acc[16];
#pragma unroll
            for (int j = 0; j < 16; j++) acc[j] = (f32x4){0.f, 0.f, 0.f, 0.f};

            const f16_t* h0b = h0hist + (size_t)t * BATCH * HID;   // cached, write-once
            const f16_t* h1r = h1buf + (size_t)((t - 1) & 1) * BATCH * HID;
#pragma unroll
            for (int i = 0; i < 8; i++) {
                const int kb = w * 8 + i;
                if (kb < 16) {
#pragma unroll
                    for (int mt = 0; mt < 4; mt++) {
                        f16x8 a = *(const f16x8*)(h0b + (size_t)(G * 64 + mt * 16 + col) * HID + kb * 32 + quad * 8);
#pragma unroll
                        for (int nt = 0; nt < 4; nt++)
                            acc[mt * 4 + nt] = __builtin_amdgcn_mfma_f32_16x16x32_f16(
                                a, Wb[i * 4 + nt], acc[mt * 4 + nt], 0, 0, 0);
                    }
                } else if (t > 0) {
#pragma unroll
                    for (int mt = 0; mt < 4; mt++) {
                        f16x8 a = ldx8(h1r + (size_t)(G * 64 + mt * 16 + col) * HID + (kb - 16) * 32 + quad * 8);
#pragma unroll
                        for (int nt = 0; nt < 4; nt++)
                            acc[mt * 4 + nt] = __builtin_amdgcn_mfma_f32_16x16x32_f16(
                                a, Wb[i * 4 + nt], acc[mt * 4 + nt], 0, 0, 0);
                    }
                }
            }
#pragma unroll
            for (int j = 0; j < 16; j++) red[w][j][lane] = acc[j];
            __syncthreads();                            // B

            // cell: wave w = m-tile mt -> 16 rows x 16 dims
            f32x4 gate[4];
#pragma unroll
            for (int nt = 0; nt < 4; nt++) {
                f32x4 v = red[0][w * 4 + nt][lane];
#pragma unroll
                for (int ww = 1; ww < 4; ww++) {
                    f32x4 p = red[ww][w * 4 + nt][lane];
#pragma unroll
                    for (int r = 0; r < 4; r++) v[r] += p[r];
                }
                gate[nt] = v;
            }
            f16_t* hout = h1buf + (size_t)(t & 1) * BATCH * HID;
#pragma unroll
            for (int r = 0; r < 4; r++) {
                float iv = sgm(gate[0][r] + bi), fv = sgm(gate[1][r] + bf);
                float gv = th(gate[2][r] + bg),  ov = sgm(gate[3][r] + bo);
                float c = fv * cst[r] + iv * gv;
                cst[r] = c;
                float h = ov * th(c);
                float hn = __shfl_down(h, 1);
                if ((lane & 1) == 0)
                    sth2a(hout + (size_t)(G * 64 + w * 16 + quad * 4 + r) * HID + s1 * 16 + col, h, hn);
            }
            __syncthreads();                            // C: all waves' stores drained
            if (tid == 0)
                __hip_atomic_store(myf1 + s1, (unsigned)it, __ATOMIC_RELAXED, SCOPE_AGT);
        }
    }
}

// out[b] = dot(h1[511][b], fc_w) + fc_b ; slot = 511&1 = 1.
__global__ void fc_k(const f16_t* __restrict__ h1buf, const float* __restrict__ fcw,
                     const float* __restrict__ fcb, float* __restrict__ out)
{
    const int b = blockIdx.x, lane = threadIdx.x;
    const f16_t* hp = h1buf + ((size_t)(BATCH + b)) * HID;
    float sum = 0.f;
#pragma unroll
    for (int j = 0; j < 8; j++) {
        const int k = lane * 8 + j;
        sum += (float)hp[k] * fcw[k];
    }
#pragma unroll
    for (int off = 32; off; off >>= 1) sum += __shfl_down(sum, off);
    if (lane == 0) out[b] = sum + fcb[0];
}

extern "C" void kernel_launch(void* const* d_in, const int* in_sizes, int n_in,
                              void* d_out, int out_size, void* d_ws, size_t ws_size,
                              hipStream_t stream)
{
    const float* x    = (const float*)d_in[0];
    const float* wih0 = (const float*)d_in[1];
    const float* whh0 = (const float*)d_in[2];
    const float* bih0 = (const float*)d_in[3];
    const float* bhh0 = (const float*)d_in[4];
    const float* wih1 = (const float*)d_in[5];
    const float* whh1 = (const float*)d_in[6];
    const float* bih1 = (const float*)d_in[7];
    const float* bhh1 = (const float*)d_in[8];
    const float* fcw  = (const float*)d_in[9];
    const float* fcb  = (const float*)d_in[10];
    float* out = (float*)d_out;

    unsigned char* ws = (unsigned char*)d_ws;
    unsigned* f0m = (unsigned*)ws;                // 8 groups * 64 dwords = 2 KB
    unsigned* f1  = (unsigned*)(ws + 2048);       // 4 groups * 32 dwords = 512 B
    f16_t* h1buf  = (f16_t*)(ws + 4096);          // 2 slots * 256*512 f16 = 512 KB
    f16_t* h0hist = (f16_t*)(ws + 4096 + 2 * BATCH * HID * sizeof(f16_t));  // 128 MB

    hipMemsetAsync(ws, 0, 4096, stream);          // zero epoch flags
    lstm_pipe<<<dim3(256), dim3(256), 0, stream>>>(x, wih0, whh0, bih0, bhh0,
                                                   wih1, whh1, bih1, bhh1,
                                                   f0m, f1, h1buf, h0hist);
    fc_k<<<dim3(BATCH), dim3(64), 0, stream>>>(h1buf, fcw, fcb, out);
}